// Round 4
// baseline (147.802 us; speedup 1.0000x reference)
//
#include <hip/hip_runtime.h>
#include <hip/hip_bf16.h>

typedef __bf16 bf16x8 __attribute__((ext_vector_type(8)));
typedef float f32x4 __attribute__((ext_vector_type(4)));
typedef float f32x16 __attribute__((ext_vector_type(16)));
typedef unsigned short u16;
typedef u16 u16x8 __attribute__((ext_vector_type(8)));

__device__ __forceinline__ u16 f2bf(float f) {
  union { float f; unsigned u; } v; v.f = f;
  unsigned r = v.u + 0x7fffu + ((v.u >> 16) & 1u);
  return (u16)(r >> 16);
}
__device__ __forceinline__ float bf2f(u16 u) {
  union { unsigned u; float f; } v; v.u = (unsigned)u << 16; return v.f;
}
__device__ __forceinline__ unsigned cvtpk(float a, float b) {
  unsigned r;
  asm("v_cvt_pk_bf16_f32 %0, %1, %2" : "=v"(r) : "v"(a), "v"(b));
  return r;
}
__device__ __forceinline__ float exp2_(float x) {
  float r;
  asm("v_exp_f32 %0, %1" : "=v"(r) : "v"(x));
  return r;
}
// async global->LDS, 16B per lane, dest = wave-uniform base + lane*16
__device__ __forceinline__ void gload16(const void* g, void* l) {
  __builtin_amdgcn_global_load_lds(
      (__attribute__((address_space(1))) void*)(void*)g,
      (__attribute__((address_space(3))) void*)l, 16, 0, 0);
}

union U8 { bf16x8 v; unsigned u[4]; };

// ---------------- cast x: f32 -> bf16, 8 elems/thread ----------------
__global__ __launch_bounds__(256) void cast_x_k(const float* __restrict__ x,
                                                u16* __restrict__ xb, int n8) {
  int id = blockIdx.x * 256 + threadIdx.x;
  if (id >= n8) return;
  const float4* p = (const float4*)(x + (size_t)id * 8);
  float4 a = p[0], b = p[1];
  u16x8 o;
  o[0] = f2bf(a.x); o[1] = f2bf(a.y); o[2] = f2bf(a.z); o[3] = f2bf(a.w);
  o[4] = f2bf(b.x); o[5] = f2bf(b.y); o[6] = f2bf(b.z); o[7] = f2bf(b.w);
  *(u16x8*)(xb + (size_t)id * 8) = o;
}

// ------------- transpose-cast W [R][Cc] f32 -> Wt [Cc][R] bf16 -------------
__global__ __launch_bounds__(256) void tcast_k(const float* __restrict__ W,
                                               u16* __restrict__ Wt, int R, int Cc) {
  __shared__ float tile[32][33];
  int bx = blockIdx.x * 32, by = blockIdx.y * 32;
  int tx = threadIdx.x & 31, ty = threadIdx.x >> 5;
#pragma unroll
  for (int j = 0; j < 4; j++)
    tile[ty + j * 8][tx] = W[(size_t)(by + ty + j * 8) * Cc + bx + tx];
  __syncthreads();
#pragma unroll
  for (int j = 0; j < 4; j++)
    Wt[(size_t)(bx + ty + j * 8) * R + by + tx] = f2bf(tile[tx][ty + j * 8]);
}

// ---------------- GEMM: C[M][N] = A[M][K](bf16) * Bt[N][K](bf16) + bias ----------------
template <bool BF16OUT>
__global__ __launch_bounds__(256) void gemm_bt_k(const u16* __restrict__ A,
                                                 const u16* __restrict__ Bt,
                                                 const float* __restrict__ bias,
                                                 void* __restrict__ Cv,
                                                 int M, int N, int K) {
  __shared__ u16 As[128 * 64];
  __shared__ u16 Bs[128 * 64];
  int tid = threadIdx.x;
  int m0 = blockIdx.y * 128, n0 = blockIdx.x * 128;
  int wave = tid >> 6, lane = tid & 63;
  int wm = (wave & 1) * 64, wn = (wave >> 1) * 64;
  int lrow = lane & 15, lk = (lane >> 4) * 8;
  int rr = lane >> 3, cb = (lane & 7) * 16;

  f32x4 acc[4][4] = {};

  for (int k0 = 0; k0 < K; k0 += 64) {
#pragma unroll
    for (int i = 0; i < 4; i++) {
      int row = wave * 32 + i * 8 + rr;
      int cc = (cb ^ ((row & 7) << 4)) >> 1;
      gload16(A + (size_t)(m0 + row) * K + k0 + cc, &As[(wave * 32 + i * 8) * 64]);
      gload16(Bt + (size_t)(n0 + row) * K + k0 + cc, &Bs[(wave * 32 + i * 8) * 64]);
    }
    __syncthreads();
#pragma unroll
    for (int kk = 0; kk < 2; kk++) {
      bf16x8 af[4], bfr[4];
#pragma unroll
      for (int i = 0; i < 4; i++) {
        int arow = wm + i * 16 + lrow;
        int ab = (arow * 128 + (kk * 32 + lk) * 2) ^ ((arow & 7) << 4);
        af[i] = *(const bf16x8*)((const char*)As + ab);
        int brow = wn + i * 16 + lrow;
        int bb = (brow * 128 + (kk * 32 + lk) * 2) ^ ((brow & 7) << 4);
        bfr[i] = *(const bf16x8*)((const char*)Bs + bb);
      }
#pragma unroll
      for (int i = 0; i < 4; i++)
#pragma unroll
        for (int j = 0; j < 4; j++)
          acc[i][j] = __builtin_amdgcn_mfma_f32_16x16x32_bf16(af[i], bfr[j], acc[i][j], 0, 0, 0);
    }
    __syncthreads();
  }
  int rg = lane >> 4;
#pragma unroll
  for (int i = 0; i < 4; i++) {
#pragma unroll
    for (int j = 0; j < 4; j++) {
      int col = n0 + wn + j * 16 + lrow;
      float bz = bias ? bias[col] : 0.f;
#pragma unroll
      for (int r = 0; r < 4; r++) {
        int row = m0 + wm + i * 16 + rg * 4 + r;
        float val = acc[i][j][r] + bz;
        if constexpr (BF16OUT)
          ((u16*)Cv)[(size_t)row * N + col] = f2bf(val);
        else
          ((float*)Cv)[(size_t)row * N + col] = val;
      }
    }
  }
}

// ---------------- RoPE on q,k (bf16 in); Q pre-scaled by 0.125*log2e ----------------
__global__ __launch_bounds__(256) void rope_qk_k(const u16* __restrict__ qkv,
                                                 u16* __restrict__ qb,
                                                 u16* __restrict__ kb) {
  int id = blockIdx.x * 256 + threadIdx.x;
  int i = id & 31;
  int h = (id >> 5) & 15;
  int t = (id >> 9) & 2047;
  int b = id >> 20;
  size_t row = (size_t)b * 2048 + t;
  const u16* base = qkv + row * 3072 + h * 64 + 2 * i;
  ushort2 qp = *(const ushort2*)(base);
  ushort2 kp = *(const ushort2*)(base + 1024);
  float qx = bf2f(qp.x), qy = bf2f(qp.y), kx = bf2f(kp.x), ky = bf2f(kp.y);
  float freq = exp2f((float)i * -0.41524101186092029f);
  float ang = (float)t * freq;
  float sv, cv;
  sincosf(ang, &sv, &cv);
  const float QS = 0.18033688011112042f;  // 0.125 * log2(e)
  size_t obase = (((size_t)(b * 16 + h) * 2048) + t) * 64 + 2 * i;
  ushort2 qo, ko;
  qo.x = f2bf((qx * cv - qy * sv) * QS); qo.y = f2bf((qx * sv + qy * cv) * QS);
  ko.x = f2bf(kx * cv - ky * sv);        ko.y = f2bf(kx * sv + ky * cv);
  *(ushort2*)(qb + obase) = qo;
  *(ushort2*)(kb + obase) = ko;
}

// ---------------- V transpose (bf16 in): (B,H,dk,T), conflict-free u32 LDS ----------------
__global__ __launch_bounds__(256) void v_trans_k(const u16* __restrict__ qkv,
                                                 u16* __restrict__ vt) {
  __shared__ unsigned tl[64][33];
  int bh = blockIdx.x;
  int t0 = blockIdx.y * 64;
  int b = bh >> 4, h = bh & 15;
  int tid = threadIdx.x;
#pragma unroll
  for (int i = 0; i < 2; i++) {
    int tr = i * 32 + (tid >> 3);
    const u16* src = qkv + ((size_t)(b * 2048 + t0 + tr)) * 3072 + 2048 + h * 64 + (tid & 7) * 8;
    u16x8 v = *(const u16x8*)src;
    const unsigned* p = (const unsigned*)&v;
    int dp0 = (tid & 7) * 4;
#pragma unroll
    for (int k = 0; k < 4; k++) tl[tr][dp0 + k] = p[k];
  }
  __syncthreads();
  u16* dst = vt + (size_t)bh * 64 * 2048;
  int t = tid & 63;
#pragma unroll
  for (int jj = 0; jj < 8; jj++) {
    int dp = jj * 4 + (tid >> 6);
    unsigned w = tl[t][dp];
    dst[(size_t)(2 * dp) * 2048 + t0 + t] = (u16)(w & 0xffff);
    dst[(size_t)(2 * dp + 1) * 2048 + t0 + t] = (u16)(w >> 16);
  }
}

// ---------------- flash attention v4: LDS-free, reg-prefetch, uniform blocks ----------------
// 512 blocks x 4 waves. Block = one qt, 4 bh (bh group pinned per XCD -> KV L2-resident).
// Per iteration: 64 KV rows as two independent 32-row S^T chains; K frags prefetched
// one iter ahead into named register sets (manual 2x unroll); V loaded in-body.

#define ATT_PREF(Pa, Pb, IT)                                                      \
  do {                                                                            \
    size_t kv_ = (size_t)(IT) * 64;                                               \
    _Pragma("unroll") for (int d_ = 0; d_ < 4; d_++) {                            \
      Pa[d_] = *(const bf16x8*)(Kp + (kv_ + ql) * 64 + d_ * 16 + hq);             \
      Pb[d_] = *(const bf16x8*)(Kp + (kv_ + 32 + ql) * 64 + d_ * 16 + hq);        \
    }                                                                             \
  } while (0)

#define ATT_BODY(Pa, Pb, IT)                                                      \
  do {                                                                            \
    int kv0_ = (IT) * 64;                                                         \
    f32x16 sa = {}, sb = {};                                                      \
    _Pragma("unroll") for (int d_ = 0; d_ < 4; d_++) {                            \
      sa = __builtin_amdgcn_mfma_f32_32x32x16_bf16(Pa[d_], qf[d_], sa, 0, 0, 0);  \
      sb = __builtin_amdgcn_mfma_f32_32x32x16_bf16(Pb[d_], qf[d_], sb, 0, 0, 0);  \
    }                                                                             \
    bf16x8 v0_[4], v1_[4];                                                        \
    _Pragma("unroll") for (int s_ = 0; s_ < 4; s_++) {                            \
      v0_[s_] = *(const bf16x8*)(Vp + (size_t)ql * 2048 + kv0_ + s_ * 16 + hq);   \
      v1_[s_] = *(const bf16x8*)(Vp + (size_t)(32 + ql) * 2048 + kv0_ + s_ * 16 + hq); \
    }                                                                             \
    if ((IT) == nIter - 1) {                                                      \
      _Pragma("unroll") for (int r_ = 0; r_ < 16; r_++) {                         \
        int ro_ = (r_ & 3) + 8 * (r_ >> 2) + 4 * hi;                              \
        if (kv0_ + ro_ > qg) sa[r_] = -3e38f;                                     \
        if (kv0_ + 32 + ro_ > qg) sb[r_] = -3e38f;                                \
      }                                                                           \
    }                                                                             \
    float ta_ = -3e38f, tb_ = -3e38f;                                             \
    _Pragma("unroll") for (int r_ = 0; r_ < 8; r_++) {                            \
      ta_ = fmaxf(ta_, fmaxf(sa[r_], sa[r_ + 8]));                                \
      tb_ = fmaxf(tb_, fmaxf(sb[r_], sb[r_ + 8]));                                \
    }                                                                             \
    float tmax_ = fmaxf(ta_, tb_);                                                \
    tmax_ = fmaxf(tmax_, __shfl_xor(tmax_, 32));                                  \
    if (!__all(tmax_ <= m + 11.5409f)) {                                          \
      float mn_ = fmaxf(m, tmax_);                                                \
      float corr_ = exp2_(m - mn_);                                               \
      m = mn_;                                                                    \
      l *= corr_;                                                                 \
      _Pragma("unroll") for (int r_ = 0; r_ < 16; r_++) {                         \
        o0[r_] *= corr_; o1[r_] *= corr_;                                         \
      }                                                                           \
    }                                                                             \
    _Pragma("unroll") for (int r_ = 0; r_ < 16; r_++) {                           \
      sa[r_] = exp2_(sa[r_] - m);                                                 \
      sb[r_] = exp2_(sb[r_] - m);                                                 \
    }                                                                             \
    float tsa_ = 0.f, tsb_ = 0.f;                                                 \
    _Pragma("unroll") for (int r_ = 0; r_ < 16; r_++) { tsa_ += sa[r_]; tsb_ += sb[r_]; } \
    float ts_ = tsa_ + tsb_;                                                      \
    ts_ += __shfl_xor(ts_, 32);                                                   \
    l += ts_;                                                                     \
    unsigned wA_[8], xA_[8], wB_[8], xB_[8];                                      \
    _Pragma("unroll") for (int j_ = 0; j_ < 8; j_++) {                            \
      wA_[j_] = cvtpk(sa[2 * j_], sa[2 * j_ + 1]);                                \
      wB_[j_] = cvtpk(sb[2 * j_], sb[2 * j_ + 1]);                                \
    }                                                                             \
    _Pragma("unroll") for (int j_ = 0; j_ < 8; j_++) {                            \
      xA_[j_] = (unsigned)__shfl_xor((int)wA_[j_], 32);                           \
      xB_[j_] = (unsigned)__shfl_xor((int)wB_[j_], 32);                           \
    }                                                                             \
    U8 pf0_, pf1_, pf2_, pf3_;                                                    \
    pf0_.u[0] = hi ? xA_[2] : wA_[0]; pf0_.u[1] = hi ? xA_[3] : wA_[1];           \
    pf0_.u[2] = hi ? wA_[2] : xA_[0]; pf0_.u[3] = hi ? wA_[3] : xA_[1];           \
    pf1_.u[0] = hi ? xA_[6] : wA_[4]; pf1_.u[1] = hi ? xA_[7] : wA_[5];           \
    pf1_.u[2] = hi ? wA_[6] : xA_[4]; pf1_.u[3] = hi ? wA_[7] : xA_[5];           \
    pf2_.u[0] = hi ? xB_[2] : wB_[0]; pf2_.u[1] = hi ? xB_[3] : wB_[1];           \
    pf2_.u[2] = hi ? wB_[2] : xB_[0]; pf2_.u[3] = hi ? wB_[3] : xB_[1];           \
    pf3_.u[0] = hi ? xB_[6] : wB_[4]; pf3_.u[1] = hi ? xB_[7] : wB_[5];           \
    pf3_.u[2] = hi ? wB_[6] : xB_[4]; pf3_.u[3] = hi ? wB_[7] : xB_[5];           \
    o0 = __builtin_amdgcn_mfma_f32_32x32x16_bf16(v0_[0], pf0_.v, o0, 0, 0, 0);    \
    o1 = __builtin_amdgcn_mfma_f32_32x32x16_bf16(v1_[0], pf0_.v, o1, 0, 0, 0);    \
    o0 = __builtin_amdgcn_mfma_f32_32x32x16_bf16(v0_[1], pf1_.v, o0, 0, 0, 0);    \
    o1 = __builtin_amdgcn_mfma_f32_32x32x16_bf16(v1_[1], pf1_.v, o1, 0, 0, 0);    \
    o0 = __builtin_amdgcn_mfma_f32_32x32x16_bf16(v0_[2], pf2_.v, o0, 0, 0, 0);    \
    o1 = __builtin_amdgcn_mfma_f32_32x32x16_bf16(v1_[2], pf2_.v, o1, 0, 0, 0);    \
    o0 = __builtin_amdgcn_mfma_f32_32x32x16_bf16(v0_[3], pf3_.v, o0, 0, 0, 0);    \
    o1 = __builtin_amdgcn_mfma_f32_32x32x16_bf16(v1_[3], pf3_.v, o1, 0, 0, 0);    \
  } while (0)

__global__ __launch_bounds__(256) void attn_k(const u16* __restrict__ Q,
                                              const u16* __restrict__ Kb,
                                              const u16* __restrict__ Vt,
                                              u16* __restrict__ Os) {
  const int T = 2048;
  int blk = blockIdx.x;
  int g = blk & 7;                       // XCD group (bh locality)
  int s = blk >> 3;                      // 0..63
  int qt = (s < 32) ? s : 95 - s;        // folded: same-XCD pairs sum ~const
  int wave = threadIdx.x >> 6, lane = threadIdx.x & 63;
  int bh = g * 4 + wave;
  int qw0 = qt * 32;
  int ql = lane & 31, hi = lane >> 5, hq = hi * 8;
  int qg = qw0 + ql;
  int nIter = (qt >> 1) + 1;             // ceil((qt+1)/2) 64-row iterations
  const u16* Qp = Q + (size_t)bh * T * 64;
  const u16* Kp = Kb + (size_t)bh * T * 64;
  const u16* Vp = Vt + (size_t)bh * 64 * T;

  bf16x8 qf[4];
#pragma unroll
  for (int ds = 0; ds < 4; ds++)
    qf[ds] = *(const bf16x8*)(Qp + (size_t)(qw0 + ql) * 64 + ds * 16 + hq);

  f32x16 o0 = {}, o1 = {};
  float m = -1e30f, l = 0.f;

  bf16x8 Aa[4], Ab[4], Ba[4], Bb[4];  // two named K-prefetch sets
  ATT_PREF(Aa, Ab, 0);
  int it = 0;
  while (true) {
    if (it + 1 < nIter) ATT_PREF(Ba, Bb, it + 1);
    ATT_BODY(Aa, Ab, it);
    if (++it >= nIter) break;
    if (it + 1 < nIter) ATT_PREF(Aa, Ab, it + 1);
    ATT_BODY(Ba, Bb, it);
    if (++it >= nIter) break;
  }

  // ---- epilogue: O = O^T/l, fused head re-interleave into (B*T, C) bf16 ----
  float inv = 1.f / l;
  int b = bh >> 4, h = bh & 15;
  u16* orow = Os + ((size_t)(b * T + qg)) * 1024 + h * 64;
#pragma unroll
  for (int j = 0; j < 4; j++) {
    ushort4 o;
    o.x = f2bf(o0[4 * j + 0] * inv); o.y = f2bf(o0[4 * j + 1] * inv);
    o.z = f2bf(o0[4 * j + 2] * inv); o.w = f2bf(o0[4 * j + 3] * inv);
    *(ushort4*)(orow + 8 * j + 4 * hi) = o;
    ushort4 q;
    q.x = f2bf(o1[4 * j + 0] * inv); q.y = f2bf(o1[4 * j + 1] * inv);
    q.z = f2bf(o1[4 * j + 2] * inv); q.w = f2bf(o1[4 * j + 3] * inv);
    *(ushort4*)(orow + 32 + 8 * j + 4 * hi) = q;
  }
}

extern "C" void kernel_launch(void* const* d_in, const int* in_sizes, int n_in,
                              void* d_out, int out_size, void* d_ws, size_t ws_size,
                              hipStream_t stream) {
  const float* x      = (const float*)d_in[0];
  const float* W_qkv  = (const float*)d_in[1];
  const float* b_qkv  = (const float*)d_in[2];
  const float* W_proj = (const float*)d_in[3];
  const float* b_proj = (const float*)d_in[4];
  float* out = (float*)d_out;

  const int B = 2, T = 2048, C = 1024;
  const int M = B * T;  // 4096

  char* ws = (char*)d_ws;
  u16* xb     = (u16*)(ws);                       // 8 MB
  u16* wqkvt  = (u16*)(ws + (8ull << 20));        // 6 MB
  u16* wprojt = (u16*)(ws + (14ull << 20));       // 2 MB
  u16* qb     = (u16*)(ws + (16ull << 20));       // 8 MB
  u16* kb     = (u16*)(ws + (24ull << 20));       // 8 MB
  u16* vt     = (u16*)(ws + (32ull << 20));       // 8 MB
  u16* sc     = (u16*)(ws + (40ull << 20));       // 8 MB
  u16* qkvb   = (u16*)(ws + (48ull << 20));       // 24 MB (bf16 qkv)

  cast_x_k<<<(M * C / 8 + 255) / 256, 256, 0, stream>>>(x, xb, M * C / 8);
  tcast_k<<<dim3(3 * C / 32, C / 32), 256, 0, stream>>>(W_qkv, wqkvt, C, 3 * C);
  tcast_k<<<dim3(C / 32, C / 32), 256, 0, stream>>>(W_proj, wprojt, C, C);
  gemm_bt_k<true><<<dim3(3 * C / 128, M / 128), 256, 0, stream>>>(xb, wqkvt, b_qkv, qkvb, M, 3 * C, C);
  rope_qk_k<<<(B * T * 16 * 32) / 256, 256, 0, stream>>>(qkvb, qb, kb);
  v_trans_k<<<dim3(B * 16, T / 64), 256, 0, stream>>>(qkvb, vt);
  attn_k<<<512, 256, 0, stream>>>(qb, kb, vt, sc);
  gemm_bt_k<false><<<dim3(C / 128, M / 128), 256, 0, stream>>>(sc, wprojt, b_proj, out, M, C, C);
}

// Round 5
// 132.905 us; speedup vs baseline: 1.1121x; 1.1121x over previous
//
#include <hip/hip_runtime.h>
#include <hip/hip_bf16.h>

typedef __bf16 bf16x8 __attribute__((ext_vector_type(8)));
typedef float f32x4 __attribute__((ext_vector_type(4)));
typedef float f32x16 __attribute__((ext_vector_type(16)));
typedef unsigned short u16;
typedef u16 u16x8 __attribute__((ext_vector_type(8)));

__device__ __forceinline__ u16 f2bf(float f) {
  union { float f; unsigned u; } v; v.f = f;
  unsigned r = v.u + 0x7fffu + ((v.u >> 16) & 1u);
  return (u16)(r >> 16);
}
__device__ __forceinline__ float bf2f(u16 u) {
  union { unsigned u; float f; } v; v.u = (unsigned)u << 16; return v.f;
}
__device__ __forceinline__ unsigned cvtpk(float a, float b) {
  unsigned r;
  asm("v_cvt_pk_bf16_f32 %0, %1, %2" : "=v"(r) : "v"(a), "v"(b));
  return r;
}
__device__ __forceinline__ float exp2_(float x) {
  float r;
  asm("v_exp_f32 %0, %1" : "=v"(r) : "v"(x));
  return r;
}
// async global->LDS, 16B per lane, dest = wave-uniform base + lane*16
__device__ __forceinline__ void gload16(const void* g, void* l) {
  __builtin_amdgcn_global_load_lds(
      (__attribute__((address_space(1))) void*)(void*)g,
      (__attribute__((address_space(3))) void*)l, 16, 0, 0);
}

union U8 { bf16x8 v; unsigned u[4]; };

// ---------------- cast x: f32 -> bf16, 8 elems/thread ----------------
__global__ __launch_bounds__(256) void cast_x_k(const float* __restrict__ x,
                                                u16* __restrict__ xb, int n8) {
  int id = blockIdx.x * 256 + threadIdx.x;
  if (id >= n8) return;
  const float4* p = (const float4*)(x + (size_t)id * 8);
  float4 a = p[0], b = p[1];
  u16x8 o;
  o[0] = f2bf(a.x); o[1] = f2bf(a.y); o[2] = f2bf(a.z); o[3] = f2bf(a.w);
  o[4] = f2bf(b.x); o[5] = f2bf(b.y); o[6] = f2bf(b.z); o[7] = f2bf(b.w);
  *(u16x8*)(xb + (size_t)id * 8) = o;
}

// ------------- transpose-cast W [R][Cc] f32 -> Wt [Cc][R] bf16 -------------
__global__ __launch_bounds__(256) void tcast_k(const float* __restrict__ W,
                                               u16* __restrict__ Wt, int R, int Cc) {
  __shared__ float tile[32][33];
  int bx = blockIdx.x * 32, by = blockIdx.y * 32;
  int tx = threadIdx.x & 31, ty = threadIdx.x >> 5;
#pragma unroll
  for (int j = 0; j < 4; j++)
    tile[ty + j * 8][tx] = W[(size_t)(by + ty + j * 8) * Cc + bx + tx];
  __syncthreads();
#pragma unroll
  for (int j = 0; j < 4; j++)
    Wt[(size_t)(bx + ty + j * 8) * R + by + tx] = f2bf(tile[tx][ty + j * 8]);
}

// ---------------- GEMM: C[M][N] = A[M][K](bf16) * Bt[N][K](bf16) + bias ----------------
template <bool BF16OUT>
__global__ __launch_bounds__(256) void gemm_bt_k(const u16* __restrict__ A,
                                                 const u16* __restrict__ Bt,
                                                 const float* __restrict__ bias,
                                                 void* __restrict__ Cv,
                                                 int M, int N, int K) {
  __shared__ u16 As[128 * 64];
  __shared__ u16 Bs[128 * 64];
  int tid = threadIdx.x;
  int m0 = blockIdx.y * 128, n0 = blockIdx.x * 128;
  int wave = tid >> 6, lane = tid & 63;
  int wm = (wave & 1) * 64, wn = (wave >> 1) * 64;
  int lrow = lane & 15, lk = (lane >> 4) * 8;
  int rr = lane >> 3, cb = (lane & 7) * 16;

  f32x4 acc[4][4] = {};

  for (int k0 = 0; k0 < K; k0 += 64) {
#pragma unroll
    for (int i = 0; i < 4; i++) {
      int row = wave * 32 + i * 8 + rr;
      int cc = (cb ^ ((row & 7) << 4)) >> 1;
      gload16(A + (size_t)(m0 + row) * K + k0 + cc, &As[(wave * 32 + i * 8) * 64]);
      gload16(Bt + (size_t)(n0 + row) * K + k0 + cc, &Bs[(wave * 32 + i * 8) * 64]);
    }
    __syncthreads();
#pragma unroll
    for (int kk = 0; kk < 2; kk++) {
      bf16x8 af[4], bfr[4];
#pragma unroll
      for (int i = 0; i < 4; i++) {
        int arow = wm + i * 16 + lrow;
        int ab = (arow * 128 + (kk * 32 + lk) * 2) ^ ((arow & 7) << 4);
        af[i] = *(const bf16x8*)((const char*)As + ab);
        int brow = wn + i * 16 + lrow;
        int bb = (brow * 128 + (kk * 32 + lk) * 2) ^ ((brow & 7) << 4);
        bfr[i] = *(const bf16x8*)((const char*)Bs + bb);
      }
#pragma unroll
      for (int i = 0; i < 4; i++)
#pragma unroll
        for (int j = 0; j < 4; j++)
          acc[i][j] = __builtin_amdgcn_mfma_f32_16x16x32_bf16(af[i], bfr[j], acc[i][j], 0, 0, 0);
    }
    __syncthreads();
  }
  int rg = lane >> 4;
#pragma unroll
  for (int i = 0; i < 4; i++) {
#pragma unroll
    for (int j = 0; j < 4; j++) {
      int col = n0 + wn + j * 16 + lrow;
      float bz = bias ? bias[col] : 0.f;
#pragma unroll
      for (int r = 0; r < 4; r++) {
        int row = m0 + wm + i * 16 + rg * 4 + r;
        float val = acc[i][j][r] + bz;
        if constexpr (BF16OUT)
          ((u16*)Cv)[(size_t)row * N + col] = f2bf(val);
        else
          ((float*)Cv)[(size_t)row * N + col] = val;
      }
    }
  }
}

// ---------------- RoPE on q,k (bf16 in); Q pre-scaled by 0.125*log2e ----------------
// Q -> (B,H,T,dk) row layout. K -> fragment-major Kf:
// Kf[((bh*32+kt)*2+half)*2048 + d*512 + (hi*32+ql)*8 + j] = K[bh][kt*64+half*32+ql][d*16+hi*8+j]
__global__ __launch_bounds__(256) void rope_qk_k(const u16* __restrict__ qkv,
                                                 u16* __restrict__ qb,
                                                 u16* __restrict__ kfb) {
  int id = blockIdx.x * 256 + threadIdx.x;
  int i = id & 31;
  int h = (id >> 5) & 15;
  int t = (id >> 9) & 2047;
  int b = id >> 20;
  size_t row = (size_t)b * 2048 + t;
  const u16* base = qkv + row * 3072 + h * 64 + 2 * i;
  ushort2 qp = *(const ushort2*)(base);
  ushort2 kp = *(const ushort2*)(base + 1024);
  float qx = bf2f(qp.x), qy = bf2f(qp.y), kx = bf2f(kp.x), ky = bf2f(kp.y);
  float freq = exp2f((float)i * -0.41524101186092029f);
  float ang = (float)t * freq;
  float sv, cv;
  sincosf(ang, &sv, &cv);
  const float QS = 0.18033688011112042f;  // 0.125 * log2(e)
  int bh = b * 16 + h;
  size_t obase = (((size_t)bh * 2048) + t) * 64 + 2 * i;
  ushort2 qo, ko;
  qo.x = f2bf((qx * cv - qy * sv) * QS); qo.y = f2bf((qx * sv + qy * cv) * QS);
  ko.x = f2bf(kx * cv - ky * sv);        ko.y = f2bf(kx * sv + ky * cv);
  *(ushort2*)(qb + obase) = qo;
  int de = 2 * i;
  size_t kidx = (((size_t)bh * 32 + (t >> 6)) * 2 + ((t >> 5) & 1)) * 2048 +
                (de >> 4) * 512 + (((de >> 3) & 1) * 32 + (t & 31)) * 8 + (de & 7);
  *(ushort2*)(kfb + kidx) = ko;
}

// ---------------- V pack fragment-major: ----------------
// Vf[(bh*32+kt)*4096 + dh*2048 + s*512 + (hi*32+ql)*8 + j] = V[bh][kt*64+s*16+hi*8+j][dh*32+ql]
__global__ __launch_bounds__(256) void v_pack_k(const u16* __restrict__ qkv,
                                                u16* __restrict__ vf) {
  __shared__ u16 tl[64][72];
  int bh = blockIdx.x, kt = blockIdx.y;
  int b = bh >> 4, h = bh & 15;
  int tid = threadIdx.x;
#pragma unroll
  for (int rep = 0; rep < 2; rep++) {
    int tr = rep * 32 + (tid >> 3);
    int dc = (tid & 7) * 8;
    u16x8 v = *(const u16x8*)(qkv + ((size_t)(b * 2048 + kt * 64 + tr)) * 3072 + 2048 + h * 64 + dc);
    *(u16x8*)&tl[tr][dc] = v;
  }
  __syncthreads();
  u16* dst = vf + ((size_t)bh * 32 + kt) * 4096;
#pragma unroll
  for (int rep = 0; rep < 2; rep++) {
    int c = rep * 256 + tid;
    int dh = c >> 8, s = (c >> 6) & 3, l = c & 63;
    int hi = l >> 5, ql = l & 31;
    u16x8 o;
#pragma unroll
    for (int j = 0; j < 8; j++) o[j] = tl[s * 16 + hi * 8 + j][dh * 32 + ql];
    *(u16x8*)(dst + (size_t)c * 8) = o;
  }
}

// ---------------- flash attention v5: fragment-major coalesced, uniform waves ----------------
// 1024 blocks x 1 wave. Wave = pair {qt=p, qt=63-p} sequentially -> exactly 33 KV-tile
// iterations per wave. All fragment loads lane-linear (1 KB / instruction).

#define ATT_PREF(Pa, Pb, IT)                                                      \
  do {                                                                            \
    const u16* kb_ = KfP + (size_t)(IT) * 4096 + ln8;                             \
    _Pragma("unroll") for (int d_ = 0; d_ < 4; d_++) {                            \
      Pa[d_] = *(const bf16x8*)(kb_ + d_ * 512);                                  \
      Pb[d_] = *(const bf16x8*)(kb_ + 2048 + d_ * 512);                           \
    }                                                                             \
  } while (0)

#define ATT_BODY(Pa, Pb, IT)                                                      \
  do {                                                                            \
    int kv0_ = (IT) * 64;                                                         \
    const u16* vb_ = VfP + (size_t)(IT) * 4096 + ln8;                             \
    f32x16 sa = {}, sb = {};                                                      \
    _Pragma("unroll") for (int d_ = 0; d_ < 4; d_++) {                            \
      sa = __builtin_amdgcn_mfma_f32_32x32x16_bf16(Pa[d_], qf[d_], sa, 0, 0, 0);  \
      sb = __builtin_amdgcn_mfma_f32_32x32x16_bf16(Pb[d_], qf[d_], sb, 0, 0, 0);  \
    }                                                                             \
    bf16x8 v0_[4], v1_[4];                                                        \
    _Pragma("unroll") for (int s_ = 0; s_ < 4; s_++) {                            \
      v0_[s_] = *(const bf16x8*)(vb_ + s_ * 512);                                 \
      v1_[s_] = *(const bf16x8*)(vb_ + 2048 + s_ * 512);                          \
    }                                                                             \
    if ((IT) == nIter - 1) {                                                      \
      _Pragma("unroll") for (int r_ = 0; r_ < 16; r_++) {                         \
        int ro_ = (r_ & 3) + 8 * (r_ >> 2) + 4 * hi;                              \
        if (kv0_ + ro_ > qg) sa[r_] = -3e38f;                                     \
        if (kv0_ + 32 + ro_ > qg) sb[r_] = -3e38f;                                \
      }                                                                           \
    }                                                                             \
    float ta_ = -3e38f, tb_ = -3e38f;                                             \
    _Pragma("unroll") for (int r_ = 0; r_ < 8; r_++) {                            \
      ta_ = fmaxf(ta_, fmaxf(sa[r_], sa[r_ + 8]));                                \
      tb_ = fmaxf(tb_, fmaxf(sb[r_], sb[r_ + 8]));                                \
    }                                                                             \
    float tmax_ = fmaxf(ta_, tb_);                                                \
    tmax_ = fmaxf(tmax_, __shfl_xor(tmax_, 32));                                  \
    if (!__all(tmax_ <= m + 11.5409f)) {                                          \
      float mn_ = fmaxf(m, tmax_);                                                \
      float corr_ = exp2_(m - mn_);                                               \
      m = mn_;                                                                    \
      ls[0] *= corr_;                                                             \
      _Pragma("unroll") for (int r_ = 0; r_ < 16; r_++) {                         \
        o0[r_] *= corr_; o1[r_] *= corr_;                                         \
      }                                                                           \
    }                                                                             \
    _Pragma("unroll") for (int r_ = 0; r_ < 16; r_++) {                           \
      sa[r_] = exp2_(sa[r_] - m);                                                 \
      sb[r_] = exp2_(sb[r_] - m);                                                 \
    }                                                                             \
    unsigned wA_[8], xA_[8], wB_[8], xB_[8];                                      \
    _Pragma("unroll") for (int j_ = 0; j_ < 8; j_++) {                            \
      wA_[j_] = cvtpk(sa[2 * j_], sa[2 * j_ + 1]);                                \
      wB_[j_] = cvtpk(sb[2 * j_], sb[2 * j_ + 1]);                                \
    }                                                                             \
    _Pragma("unroll") for (int j_ = 0; j_ < 8; j_++) {                            \
      xA_[j_] = (unsigned)__shfl_xor((int)wA_[j_], 32);                           \
      xB_[j_] = (unsigned)__shfl_xor((int)wB_[j_], 32);                           \
    }                                                                             \
    U8 pf0_, pf1_, pf2_, pf3_;                                                    \
    pf0_.u[0] = hi ? xA_[2] : wA_[0]; pf0_.u[1] = hi ? xA_[3] : wA_[1];           \
    pf0_.u[2] = hi ? wA_[2] : xA_[0]; pf0_.u[3] = hi ? wA_[3] : xA_[1];           \
    pf1_.u[0] = hi ? xA_[6] : wA_[4]; pf1_.u[1] = hi ? xA_[7] : wA_[5];           \
    pf1_.u[2] = hi ? wA_[6] : xA_[4]; pf1_.u[3] = hi ? wA_[7] : xA_[5];           \
    pf2_.u[0] = hi ? xB_[2] : wB_[0]; pf2_.u[1] = hi ? xB_[3] : wB_[1];           \
    pf2_.u[2] = hi ? wB_[2] : xB_[0]; pf2_.u[3] = hi ? wB_[3] : xB_[1];           \
    pf3_.u[0] = hi ? xB_[6] : wB_[4]; pf3_.u[1] = hi ? xB_[7] : wB_[5];           \
    pf3_.u[2] = hi ? wB_[6] : xB_[4]; pf3_.u[3] = hi ? wB_[7] : xB_[5];           \
    o0 = __builtin_amdgcn_mfma_f32_32x32x16_bf16(v0_[0], pf0_.v, o0, 0, 0, 0);    \
    o1 = __builtin_amdgcn_mfma_f32_32x32x16_bf16(v1_[0], pf0_.v, o1, 0, 0, 0);    \
    o0 = __builtin_amdgcn_mfma_f32_32x32x16_bf16(v0_[1], pf1_.v, o0, 0, 0, 0);    \
    o1 = __builtin_amdgcn_mfma_f32_32x32x16_bf16(v1_[1], pf1_.v, o1, 0, 0, 0);    \
    o0 = __builtin_amdgcn_mfma_f32_32x32x16_bf16(v0_[2], pf2_.v, o0, 0, 0, 0);    \
    o1 = __builtin_amdgcn_mfma_f32_32x32x16_bf16(v1_[2], pf2_.v, o1, 0, 0, 0);    \
    o0 = __builtin_amdgcn_mfma_f32_32x32x16_bf16(v0_[3], pf3_.v, o0, 0, 0, 0);    \
    o1 = __builtin_amdgcn_mfma_f32_32x32x16_bf16(v1_[3], pf3_.v, o1, 0, 0, 0);    \
    ls = __builtin_amdgcn_mfma_f32_32x32x16_bf16(onesf.v, pf0_.v, ls, 0, 0, 0);   \
    ls = __builtin_amdgcn_mfma_f32_32x32x16_bf16(onesf.v, pf1_.v, ls, 0, 0, 0);   \
    ls = __builtin_amdgcn_mfma_f32_32x32x16_bf16(onesf.v, pf2_.v, ls, 0, 0, 0);   \
    ls = __builtin_amdgcn_mfma_f32_32x32x16_bf16(onesf.v, pf3_.v, ls, 0, 0, 0);   \
  } while (0)

__global__ __launch_bounds__(64) void attn_k(const u16* __restrict__ Q,
                                             const u16* __restrict__ Kf,
                                             const u16* __restrict__ Vf,
                                             u16* __restrict__ Os) {
  const int T = 2048;
  int blk = blockIdx.x;
  int g = blk & 7;                 // XCD group
  int bh = g * 4 + ((blk >> 3) & 3);
  int p = blk >> 5;                // 0..31
  int lane = threadIdx.x & 63;
  int ql = lane & 31, hi = lane >> 5, hq = hi * 8;
  int ln8 = lane * 8;
  const u16* Qp = Q + (size_t)bh * T * 64;
  const u16* KfP = Kf + (size_t)bh * 32 * 4096;
  const u16* VfP = Vf + (size_t)bh * 32 * 4096;
  int b = bh >> 4, h = bh & 15;

  U8 onesf;
#pragma unroll
  for (int j = 0; j < 4; j++) onesf.u[j] = 0x3F803F80u;

#pragma unroll 1
  for (int ph = 0; ph < 2; ph++) {
    const int qt = ph ? 63 - p : p;
    const int qw0 = qt * 32;
    const int qg = qw0 + ql;
    const int nIter = (qt >> 1) + 1;

    bf16x8 qf[4];
#pragma unroll
    for (int ds = 0; ds < 4; ds++)
      qf[ds] = *(const bf16x8*)(Qp + (size_t)(qw0 + ql) * 64 + ds * 16 + hq);

    f32x16 o0 = {}, o1 = {}, ls = {};
    float m = -1e30f;

    bf16x8 Aa[4], Ab[4], Ba[4], Bb[4];
    ATT_PREF(Aa, Ab, 0);
    int it = 0;
    while (true) {
      if (it + 1 < nIter) ATT_PREF(Ba, Bb, it + 1);
      ATT_BODY(Aa, Ab, it);
      if (++it >= nIter) break;
      if (it + 1 < nIter) ATT_PREF(Aa, Ab, it + 1);
      ATT_BODY(Ba, Bb, it);
      if (++it >= nIter) break;
    }

    float inv = 1.f / ls[0];
    u16* orow = Os + ((size_t)(b * T + qg)) * 1024 + h * 64;
#pragma unroll
    for (int j = 0; j < 4; j++) {
      ushort4 o;
      o.x = f2bf(o0[4 * j + 0] * inv); o.y = f2bf(o0[4 * j + 1] * inv);
      o.z = f2bf(o0[4 * j + 2] * inv); o.w = f2bf(o0[4 * j + 3] * inv);
      *(ushort4*)(orow + 8 * j + 4 * hi) = o;
      ushort4 q;
      q.x = f2bf(o1[4 * j + 0] * inv); q.y = f2bf(o1[4 * j + 1] * inv);
      q.z = f2bf(o1[4 * j + 2] * inv); q.w = f2bf(o1[4 * j + 3] * inv);
      *(ushort4*)(orow + 32 + 8 * j + 4 * hi) = q;
    }
  }
}

extern "C" void kernel_launch(void* const* d_in, const int* in_sizes, int n_in,
                              void* d_out, int out_size, void* d_ws, size_t ws_size,
                              hipStream_t stream) {
  const float* x      = (const float*)d_in[0];
  const float* W_qkv  = (const float*)d_in[1];
  const float* b_qkv  = (const float*)d_in[2];
  const float* W_proj = (const float*)d_in[3];
  const float* b_proj = (const float*)d_in[4];
  float* out = (float*)d_out;

  const int B = 2, T = 2048, C = 1024;
  const int M = B * T;  // 4096

  char* ws = (char*)d_ws;
  u16* xb     = (u16*)(ws);                       // 8 MB
  u16* wqkvt  = (u16*)(ws + (8ull << 20));        // 6 MB
  u16* wprojt = (u16*)(ws + (14ull << 20));       // 2 MB
  u16* qb     = (u16*)(ws + (16ull << 20));       // 8 MB
  u16* kfb    = (u16*)(ws + (24ull << 20));       // 8 MB (fragment-major K)
  u16* vfb    = (u16*)(ws + (32ull << 20));       // 8 MB (fragment-major V)
  u16* sc     = (u16*)(ws + (40ull << 20));       // 8 MB
  u16* qkvb   = (u16*)(ws + (48ull << 20));       // 24 MB (bf16 qkv)

  cast_x_k<<<(M * C / 8 + 255) / 256, 256, 0, stream>>>(x, xb, M * C / 8);
  tcast_k<<<dim3(3 * C / 32, C / 32), 256, 0, stream>>>(W_qkv, wqkvt, C, 3 * C);
  tcast_k<<<dim3(C / 32, C / 32), 256, 0, stream>>>(W_proj, wprojt, C, C);
  gemm_bt_k<true><<<dim3(3 * C / 128, M / 128), 256, 0, stream>>>(xb, wqkvt, b_qkv, qkvb, M, 3 * C, C);
  rope_qk_k<<<(B * T * 16 * 32) / 256, 256, 0, stream>>>(qkvb, qb, kfb);
  v_pack_k<<<dim3(B * 16, T / 64), 256, 0, stream>>>(qkvb, vfb);
  attn_k<<<1024, 64, 0, stream>>>(qb, kfb, vfb, sc);
  gemm_bt_k<false><<<dim3(C / 128, M / 128), 256, 0, stream>>>(sc, wprojt, b_proj, out, M, C, C);
}